// Round 4
// baseline (600.784 us; speedup 1.0000x reference)
//
#include <hip/hip_runtime.h>
#include <hip/hip_bf16.h>

// One-hot expansion: mask [1,1,256,256,48] fp32 labels 0..40 ->
// out [1,40,256,256,48] fp32, out[n,v] = (mask[v] == n+1).
//
// R2 post-mortem: kernel ran at HBM roofline but moved ~1 GB instead of
// 516 MB — the 503 MB output stream evicted the 12.6 MB mask from LLC, so
// all 40 plane passes re-fetched mask from HBM. Fix: nontemporal stores
// for out (nt flag -> no LLC pollution), mask stays cached.
// R3: __builtin_nontemporal_store needs a native vector type, not
// HIP_vector_type — use ext_vector_type(4).

constexpr int V = 256 * 256 * 48;   // 3,145,728 voxels per plane
constexpr int N_LABELS = 40;

typedef float vfloat4 __attribute__((ext_vector_type(4)));

__global__ __launch_bounds__(256)
void onehot_kernel(const float* __restrict__ mask, float* __restrict__ out) {
    const int n = blockIdx.y;                                       // label plane
    const float lab = (float)(n + 1);
    const int i = (blockIdx.x * blockDim.x + threadIdx.x) * 8;      // 8 voxels/thread

    const vfloat4 m0 = *reinterpret_cast<const vfloat4*>(mask + i);
    const vfloat4 m1 = *reinterpret_cast<const vfloat4*>(mask + i + 4);

    vfloat4 o0, o1;
    o0.x = (m0.x == lab) ? 1.0f : 0.0f;
    o0.y = (m0.y == lab) ? 1.0f : 0.0f;
    o0.z = (m0.z == lab) ? 1.0f : 0.0f;
    o0.w = (m0.w == lab) ? 1.0f : 0.0f;
    o1.x = (m1.x == lab) ? 1.0f : 0.0f;
    o1.y = (m1.y == lab) ? 1.0f : 0.0f;
    o1.z = (m1.z == lab) ? 1.0f : 0.0f;
    o1.w = (m1.w == lab) ? 1.0f : 0.0f;

    vfloat4* dst = reinterpret_cast<vfloat4*>(out + (size_t)n * V + i);
    __builtin_nontemporal_store(o0, dst);
    __builtin_nontemporal_store(o1, dst + 1);
}

extern "C" void kernel_launch(void* const* d_in, const int* in_sizes, int n_in,
                              void* d_out, int out_size, void* d_ws, size_t ws_size,
                              hipStream_t stream) {
    const float* mask = (const float*)d_in[0];
    float* out = (float*)d_out;

    const int threads = 256;
    const int blocks_x = (V / 8) / threads;  // 1,536 chunks per plane
    dim3 grid(blocks_x, N_LABELS);           // 61,440 blocks total

    onehot_kernel<<<grid, threads, 0, stream>>>(mask, out);
}

// Round 6
// 490.542 us; speedup vs baseline: 1.2247x; 1.2247x over previous
//
#include <hip/hip_runtime.h>
#include <hip/hip_bf16.h>

// One-hot expansion: mask [1,1,256,256,48] fp32 labels 0..40 ->
// out [1,40,256,256,48] fp32, out[n,v] = (mask[v] == n+1).
//
// Journal: R1 (40 stores/thread, 16B-granularity plane interleave) = 1 TB/s.
// R2 (plane-major, cached stores) = roofline but 2x traffic (mask re-fetch
// 40x: write stream evicts it from LLC). R4: nt stores HURT write BW (L2
// write-aggregation is load-bearing) — never nt the write stream. R5:
// chunk-major dispatch slower + flaky post-timing fail; abandoned.
//
// R6: register-cached mask — no cache-policy dependence at all. One wave
// per block; each thread caches 32 mask voxels (32 VGPRs, 8 coalesced
// dwordx4 loads), then loops n=0..39 writing an 8KB contiguous run per
// plane (8 back-to-back dwordx4 stores; '#pragma unroll 1' keeps plane
// streams from interleaving). Guaranteed traffic: 12.6 MB read (once) +
// 503 MB write.

constexpr int V = 256 * 256 * 48;   // 3,145,728 voxels per plane
constexpr int N_LABELS = 40;
constexpr int THREADS = 64;                               // one wave per block
constexpr int VOX_PER_THREAD = 32;
constexpr int VOX_PER_BLOCK = THREADS * VOX_PER_THREAD;   // 2048

typedef float vfloat4 __attribute__((ext_vector_type(4)));

__global__ __launch_bounds__(THREADS)
void onehot_kernel(const float* __restrict__ mask, float* __restrict__ out) {
    const int base = blockIdx.x * VOX_PER_BLOCK;
    const int tid  = threadIdx.x;

    // Load this wave's 2048-voxel mask chunk into registers.
    // Load j, lane l covers floats [j*256 + l*4, +4) — 1KB contiguous/instr.
    vfloat4 m[8];
#pragma unroll
    for (int j = 0; j < 8; ++j)
        m[j] = *reinterpret_cast<const vfloat4*>(mask + base + j * 256 + tid * 4);

#pragma unroll 1   // keep the 40 plane-streams separate in the schedule
    for (int n = 0; n < N_LABELS; ++n) {
        const float lab = (float)(n + 1);
        float* dst = out + (size_t)n * V + base + tid * 4;
#pragma unroll
        for (int j = 0; j < 8; ++j) {
            vfloat4 o;
            o.x = (m[j].x == lab) ? 1.0f : 0.0f;
            o.y = (m[j].y == lab) ? 1.0f : 0.0f;
            o.z = (m[j].z == lab) ? 1.0f : 0.0f;
            o.w = (m[j].w == lab) ? 1.0f : 0.0f;
            *reinterpret_cast<vfloat4*>(dst + j * 256) = o;
        }
    }
}

extern "C" void kernel_launch(void* const* d_in, const int* in_sizes, int n_in,
                              void* d_out, int out_size, void* d_ws, size_t ws_size,
                              hipStream_t stream) {
    const float* mask = (const float*)d_in[0];
    float* out = (float*)d_out;

    const int blocks = V / VOX_PER_BLOCK;  // 1536 single-wave blocks (6/CU)
    onehot_kernel<<<blocks, THREADS, 0, stream>>>(mask, out);
}

// Round 7
// 483.070 us; speedup vs baseline: 1.2437x; 1.0155x over previous
//
#include <hip/hip_runtime.h>
#include <hip/hip_bf16.h>

// One-hot expansion: mask [1,1,256,256,48] fp32 labels 0..40 ->
// out [1,40,256,256,48] fp32, out[n,v] = (mask[v] == n+1).
//
// Journal: R1 fine-interleaved 40 store streams/thread = 1 TB/s. R2
// plane-major high-occupancy = full 6.3 TB/s but 2x traffic (mask
// re-fetched 40x from HBM; write stream evicts LLC). R4 nt stores hurt
// write BW (L2 write-aggregation is load-bearing). R6 register-cached
// mask w/ 1-wave blocks = ideal traffic but 3 TB/s (6 waves/CU can't
// keep enough stores in flight).
//
// R7: keep R2's proven-roofline structure, shrink the re-read instead:
// pass 1 converts mask fp32->u8 (3.1 MB) into d_ws; pass 2 is R2 with u8
// mask reads. Worst-case traffic 645 MB (vs R2's 1016 MB), best case
// ~519 MB if the 3.1 MB u8 mask stays LLC-resident.

constexpr int V = 256 * 256 * 48;   // 3,145,728 voxels per plane
constexpr int N_LABELS = 40;

typedef float vfloat4 __attribute__((ext_vector_type(4)));

// ---- Pass 1: fp32 labels -> u8, 16 voxels/thread ----
__global__ __launch_bounds__(256)
void pack_kernel(const float* __restrict__ mask, unsigned char* __restrict__ m8) {
    const int base = (blockIdx.x * 256 + threadIdx.x) * 16;
    uint4 packed;
    unsigned int* p = &packed.x;
#pragma unroll
    for (int g = 0; g < 4; ++g) {
        const vfloat4 m = *reinterpret_cast<const vfloat4*>(mask + base + g * 4);
        p[g] = (unsigned int)m.x
             | ((unsigned int)m.y << 8)
             | ((unsigned int)m.z << 16)
             | ((unsigned int)m.w << 24);
    }
    *reinterpret_cast<uint4*>(m8 + base) = packed;
}

// ---- Pass 2: u8 mask -> one-hot fp32, plane-major (R2 structure) ----
__global__ __launch_bounds__(256)
void onehot_u8_kernel(const unsigned char* __restrict__ m8, float* __restrict__ out) {
    const int n = blockIdx.y;                                   // label plane
    const unsigned int lab = (unsigned int)(n + 1);
    const int i = (blockIdx.x * 256 + threadIdx.x) * 8;         // 8 voxels/thread

    const uint2 w = *reinterpret_cast<const uint2*>(m8 + i);

    vfloat4 o0, o1;
    o0.x = (((w.x      ) & 0xffu) == lab) ? 1.0f : 0.0f;
    o0.y = (((w.x >>  8) & 0xffu) == lab) ? 1.0f : 0.0f;
    o0.z = (((w.x >> 16) & 0xffu) == lab) ? 1.0f : 0.0f;
    o0.w = (((w.x >> 24)        ) == lab) ? 1.0f : 0.0f;
    o1.x = (((w.y      ) & 0xffu) == lab) ? 1.0f : 0.0f;
    o1.y = (((w.y >>  8) & 0xffu) == lab) ? 1.0f : 0.0f;
    o1.z = (((w.y >> 16) & 0xffu) == lab) ? 1.0f : 0.0f;
    o1.w = (((w.y >> 24)        ) == lab) ? 1.0f : 0.0f;

    vfloat4* dst = reinterpret_cast<vfloat4*>(out + (size_t)n * V + i);
    dst[0] = o0;
    dst[1] = o1;
}

// ---- Fallback (known-good R2): fp32 mask direct, in case ws is tiny ----
__global__ __launch_bounds__(256)
void onehot_f32_kernel(const float* __restrict__ mask, float* __restrict__ out) {
    const int n = blockIdx.y;
    const float lab = (float)(n + 1);
    const int i = (blockIdx.x * 256 + threadIdx.x) * 8;

    const vfloat4 m0 = *reinterpret_cast<const vfloat4*>(mask + i);
    const vfloat4 m1 = *reinterpret_cast<const vfloat4*>(mask + i + 4);

    vfloat4 o0, o1;
    o0.x = (m0.x == lab) ? 1.0f : 0.0f;
    o0.y = (m0.y == lab) ? 1.0f : 0.0f;
    o0.z = (m0.z == lab) ? 1.0f : 0.0f;
    o0.w = (m0.w == lab) ? 1.0f : 0.0f;
    o1.x = (m1.x == lab) ? 1.0f : 0.0f;
    o1.y = (m1.y == lab) ? 1.0f : 0.0f;
    o1.z = (m1.z == lab) ? 1.0f : 0.0f;
    o1.w = (m1.w == lab) ? 1.0f : 0.0f;

    vfloat4* dst = reinterpret_cast<vfloat4*>(out + (size_t)n * V + i);
    dst[0] = o0;
    dst[1] = o1;
}

extern "C" void kernel_launch(void* const* d_in, const int* in_sizes, int n_in,
                              void* d_out, int out_size, void* d_ws, size_t ws_size,
                              hipStream_t stream) {
    const float* mask = (const float*)d_in[0];
    float* out = (float*)d_out;

    if (ws_size >= (size_t)V && d_ws != nullptr) {
        unsigned char* m8 = (unsigned char*)d_ws;
        pack_kernel<<<V / (256 * 16), 256, 0, stream>>>(mask, m8);
        dim3 grid(V / (256 * 8), N_LABELS);   // (1536, 40)
        onehot_u8_kernel<<<grid, 256, 0, stream>>>(m8, out);
    } else {
        dim3 grid(V / (256 * 8), N_LABELS);
        onehot_f32_kernel<<<grid, 256, 0, stream>>>(mask, out);
    }
}